// Round 4
// baseline (130.440 us; speedup 1.0000x reference)
//
#include <hip/hip_runtime.h>
#include <math.h>

#define T 2048
#define D 3
#define P 3
#define NK 11              // 2*KMAX+1
#define SUM_K2 110.0f      // 2*(1+4+9+16+25)
#define TWO_PI_F 6.28318530717958647692f
#define INV_TWO_PI_F 0.15915494309189533577f
#define PI_F 3.14159265358979323846f

#define SPLIT 4
#define SEG 511            // Tp / SPLIT, Tp = T-1-P = 2044 = 4*511
#define TICKET_STRIDE 32   // ints; 128 B -> one cache line per mc ticket

// Torus logmap: wrap to [-pi, pi]. Reference is floor-mod -> [-pi, pi);
// difference only at exact +/-pi boundary (measure-zero for random floats).
__device__ __forceinline__ float wrap_pi(float x) {
    float k = rintf(x * INV_TWO_PI_F);     // v_rndne_f32
    return fmaf(-k, TWO_PI_F, x);          // x - 2pi*k
}

// One block = one SEG-length segment of one series. Grid = 2048 -> 8 blocks/CU
// x 4 waves = full occupancy. Partial sums: plain disjoint stores to workspace.
// The LAST block of each mc group (padded per-mc ticket, 128-B stride to avoid
// round-1's same-line atomic serialization) reduces its 64 partials with
// agent-scope loads (per-XCD L2s are non-coherent) and writes out[mc] directly
// — this removes the separate reduce_kernel launch + full-grid drain barrier.
__global__ __launch_bounds__(256) void arp_kernel(
    const float* __restrict__ g,
    const float* __restrict__ ar_phi,   // (D,P)
    const float* __restrict__ ar_eta,   // (D,)
    const float* __restrict__ ar_c,     // (D,)
    float* __restrict__ partial,        // (n_series*SPLIT,)   [use_ws]
    int*   __restrict__ tickets,        // (n_mc*TICKET_STRIDE) [use_ws], zeroed
    float* __restrict__ out,            // (n_mc,)
    int n_samples,
    int per_mc,                         // n_samples*SPLIT
    int use_ws)
{
    __shared__ float sg[SEG * 3 + 12 + 4];      // 1549 floats ~ 6.2 KiB
    __shared__ float sdx[(SEG + 3) * 3];        // 1542 floats ~ 6.2 KiB
    __shared__ float wave_sums[4];

    const int blk    = blockIdx.x;
    const int series = blk >> 2;               // / SPLIT
    const int seg    = blk & (SPLIT - 1);
    const int tid    = threadIdx.x;

    const int t0      = seg * SEG;             // first output timestep
    const int start_f = t0 * 3;                // first float of row t0
    const int a0      = start_f & ~3;          // float4-aligned down (<=3 extra)
    const int ofs     = start_f - a0;
    const int nfloat  = SEG * 3 + 12 + ofs;    // 1545..1548
    const int nvec    = (nfloat + 3) >> 2;     // <= 387

    // Phase 1: coalesced float4 load of the segment (+4-row halo) into LDS.
    {
        const float4* src = (const float4*)(g + (size_t)series * (T * D) + a0);
        float4* dst = (float4*)sg;
        for (int i = tid; i < nvec; i += 256) dst[i] = src[i];  // 2 iters/thread
    }
    __syncthreads();

    // Phase 2: each wrapped increment computed exactly once.
    // sdx[r*3+d] = wrap(g[t0+r+1,d] - g[t0+r,d]) ; flat f = r*3+d.
    {
        const int n = (SEG + 3) * 3;           // 1542; ~6 iters/thread
        for (int f = tid; f < n; f += 256)
            sdx[f] = wrap_pi(sg[ofs + f + 3] - sg[ofs + f]);
    }
    __syncthreads();

    // Per-dim parameters (tiny, cache-served) + analytic winding constant.
    float ph[D][P], inv_s2[D], cc[D];
    float Cd_sum = 0.0f;
    #pragma unroll
    for (int d = 0; d < D; ++d) {
        float s = fabsf(ar_eta[d]);            // scale = sqrt(eta^2)
        inv_s2[d] = 1.0f / (s * s);
        cc[d] = ar_c[d];
        #pragma unroll
        for (int j = 0; j < P; ++j) ph[d][j] = ar_phi[d * P + j];
        // Sum over 11 windings of the non-quadratic parts:
        //   -0.5/s^2 * 4pi^2 * SUM_K2  - NK*log(s) - (NK/2)*log(2pi)
        Cd_sum += -0.5f * inv_s2[d] * (4.0f * PI_F * PI_F * SUM_K2)
                  - (float)NK * logf(s)
                  - 0.5f * (float)NK * logf(TWO_PI_F);
    }

    // Phase 3: local t in [0, SEG). Lane LDS stride 12 B -> bank stride 3,
    // coprime with 32 banks -> only the free 2-way wave64 aliasing.
    float acc = 0.0f;
    for (int t = tid; t < SEG; t += 256) {     // 2 iters/thread
        float w[12];                           // dx[t..t+3][d=0..2], contiguous
        #pragma unroll
        for (int m = 0; m < 12; ++m) w[m] = sdx[t * 3 + m];
        #pragma unroll
        for (int d = 0; d < D; ++d) {
            float dy = w[9 + d] - (ph[d][0] * w[6 + d]
                                 + ph[d][1] * w[3 + d]
                                 + ph[d][2] * w[d]);
            float z = dy - cc[d];
            acc += -0.5f * (float)NK * z * z * inv_s2[d];   // -5.5 * z^2 / s^2
        }
    }

    // Wave shuffle reduction, then cross-wave via LDS.
    #pragma unroll
    for (int off = 32; off > 0; off >>= 1) acc += __shfl_down(acc, off, 64);
    const int wave = tid >> 6, lane = tid & 63;
    if (lane == 0) wave_sums[wave] = acc;
    __syncthreads();

    const int mc = series / n_samples;

    if (!use_ws) {
        if (tid == 0) {
            float block_sum = wave_sums[0] + wave_sums[1] + wave_sums[2] + wave_sums[3];
            block_sum += (float)SEG * Cd_sum;
            atomicAdd(&out[mc], block_sum);    // fallback (round-0 semantics)
        }
        return;
    }

    // Publish partial, then claim a ticket with device-scope release.
    bool last = false;
    if (tid == 0) {
        float block_sum = wave_sums[0] + wave_sums[1] + wave_sums[2] + wave_sums[3];
        block_sum += (float)SEG * Cd_sum;      // analytic constant, per segment
        partial[blk] = block_sum;              // disjoint store
        __threadfence();                       // flush to device coherence point
        int old = __hip_atomic_fetch_add(&tickets[mc * TICKET_STRIDE], 1,
                                         __ATOMIC_ACQ_REL,
                                         __HIP_MEMORY_SCOPE_AGENT);
        last = (old == per_mc - 1);
    }

    // Wave 0 of the LAST block of this mc reduces its per_mc partials.
    if (tid < 64) {
        if (__shfl(last ? 1 : 0, 0, 64)) {     // broadcast lane 0's verdict
            const int base = mc * per_mc;      // mc's partials are contiguous
            float v = 0.0f;
            if (tid < per_mc)                  // agent-scope: bypass stale L2
                v = __hip_atomic_load(&partial[base + tid],
                                      __ATOMIC_RELAXED,
                                      __HIP_MEMORY_SCOPE_AGENT);
            #pragma unroll
            for (int off = 32; off > 0; off >>= 1) v += __shfl_down(v, off, 64);
            if (tid == 0) out[mc] = v;
        }
    }
}

extern "C" void kernel_launch(void* const* d_in, const int* in_sizes, int n_in,
                              void* d_out, int out_size, void* d_ws, size_t ws_size,
                              hipStream_t stream) {
    const float* g      = (const float*)d_in[0];
    const float* ar_phi = (const float*)d_in[1];
    const float* ar_eta = (const float*)d_in[2];
    const float* ar_c   = (const float*)d_in[3];
    float* out = (float*)d_out;

    const int n_series  = in_sizes[0] / (T * D);   // n_mc * n_samples = 512
    const int n_mc      = out_size;                // 32
    const int n_samples = n_series / n_mc;         // 16
    const int n_blocks  = n_series * SPLIT;        // 2048
    const int per_mc    = n_samples * SPLIT;       // 64 partials per mc

    // Workspace layout: partial[n_blocks] | pad to 128 B | tickets[n_mc*32 ints]
    const size_t part_bytes   = (size_t)n_blocks * sizeof(float);
    const size_t ticket_off   = (part_bytes + 127) & ~(size_t)127;
    const size_t ticket_bytes = (size_t)n_mc * TICKET_STRIDE * sizeof(int);
    const size_t need         = ticket_off + ticket_bytes;

    const int use_ws = (d_ws != nullptr && ws_size >= need) ? 1 : 0;
    float* partial = (float*)d_ws;
    int*   tickets = (int*)((char*)d_ws + ticket_off);

    if (use_ws) {
        // Tickets are in poisoned workspace — must be zeroed every launch.
        hipMemsetAsync(tickets, 0, ticket_bytes, stream);
    } else {
        // d_out is poisoned (0xAA) before every timed launch — zero it.
        hipMemsetAsync(out, 0, (size_t)out_size * sizeof(float), stream);
    }
    arp_kernel<<<n_blocks, 256, 0, stream>>>(g, ar_phi, ar_eta, ar_c,
                                             partial, tickets, out,
                                             n_samples, per_mc, use_ws);
}

// Round 5
// 68.212 us; speedup vs baseline: 1.9123x; 1.9123x over previous
//
#include <hip/hip_runtime.h>
#include <math.h>

#define T 2048
#define D 3
#define P 3
#define NK 11              // 2*KMAX+1
#define SUM_K2 110.0f      // 2*(1+4+9+16+25)
#define TWO_PI_F 6.28318530717958647692f
#define INV_TWO_PI_F 0.15915494309189533577f
#define PI_F 3.14159265358979323846f

#define TP (T - 1 - P)     // 2044 outputs per series
#define OUT_PER_THREAD 4
#define OUT_PER_BLOCK 1024 // 256 threads * 4
#define BLOCKS_PER_SERIES 2

// Torus logmap: wrap to [-pi, pi]. Reference is floor-mod -> [-pi, pi);
// difference only at exact +/-pi boundary (measure-zero for random floats).
__device__ __forceinline__ float wrap_pi(float x) {
    float k = rintf(x * INV_TWO_PI_F);     // v_rndne_f32
    return fmaf(-k, TWO_PI_F, x);          // x - 2pi*k
}

// Round-4 post-mortem: per-block __threadfence() (device-scope release on
// non-coherent per-XCD L2s) cost ~60 us — kernel went 67.5 us at 1.2% HBM,
// 4.4% VALU. Reverted. Cross-kernel visibility comes free at dispatch
// boundaries (round 3 passed on that).
//
// This version removes the OTHER latency: no LDS staging, no phase barriers.
// Each thread computes 4 consecutive outputs directly from global memory:
// 6 aligned float4 loads (g rows t..t+7; 2x halo vs ideal, absorbed by L1/L2),
// 21 in-register wraps, 12 AR residuals. One memory round-trip per thread,
// full ILP. Grid = n_series*2 = 1024 blocks -> 4 blocks/CU x 4 waves.
__global__ __launch_bounds__(256) void arp_kernel(
    const float* __restrict__ g,
    const float* __restrict__ ar_phi,   // (D,P)
    const float* __restrict__ ar_eta,   // (D,)
    const float* __restrict__ ar_c,     // (D,)
    float* __restrict__ partial,        // (n_series*BLOCKS_PER_SERIES,) [use_ws]
    float* __restrict__ out,            // (n_mc,)                       [!use_ws]
    int n_samples,
    int use_ws)
{
    __shared__ float wave_sums[4];

    const int blk    = blockIdx.x;
    const int series = blk >> 1;
    const int half   = blk & 1;
    const int tid    = threadIdx.x;
    const int t      = half * OUT_PER_BLOCK + tid * OUT_PER_THREAD;

    // Per-dim parameters (tiny, L2-broadcast) + analytic winding constant.
    float ph[D][P], inv_s2[D], cc[D];
    float Cd_sum = 0.0f;
    #pragma unroll
    for (int d = 0; d < D; ++d) {
        float s = fabsf(ar_eta[d]);            // scale = sqrt(eta^2)
        inv_s2[d] = 1.0f / (s * s);
        cc[d] = ar_c[d];
        #pragma unroll
        for (int j = 0; j < P; ++j) ph[d][j] = ar_phi[d * P + j];
        // Sum over 11 windings of the non-quadratic parts:
        //   -0.5/s^2 * 4pi^2 * SUM_K2  - NK*log(s) - (NK/2)*log(2pi)
        Cd_sum += -0.5f * inv_s2[d] * (4.0f * PI_F * PI_F * SUM_K2)
                  - (float)NK * logf(s)
                  - 0.5f * (float)NK * logf(TWO_PI_F);
    }

    float acc = 0.0f;
    // TP = 2044 = 4*511 -> threads with t < TP have ALL 4 outputs valid
    // (t <= 2040, t+3 <= 2043) and their loads (rows t..t+7 <= 2047) are
    // in-bounds. Only thread 255 of odd blocks (t = 2044) is fully skipped.
    if (t < TP) {
        // 24 floats = g rows t..t+7. Byte offset 48*(global 4-output index)
        // -> 16B-aligned. 6 independent float4 loads, one latency round.
        const float4* src4 = (const float4*)(g + (size_t)series * (T * D) + t * 3);
        float4 q[6];
        #pragma unroll
        for (int m = 0; m < 6; ++m) q[m] = src4[m];

        float vv[24];
        #pragma unroll
        for (int m = 0; m < 6; ++m) {
            vv[4 * m + 0] = q[m].x;  vv[4 * m + 1] = q[m].y;
            vv[4 * m + 2] = q[m].z;  vv[4 * m + 3] = q[m].w;
        }

        // Wrapped increments dx[r][d] for r = t..t+6 (7 rows), in registers.
        float dxv[21];
        #pragma unroll
        for (int m = 0; m < 21; ++m) dxv[m] = wrap_pi(vv[m + 3] - vv[m]);

        // 4 outputs: dy[t+k][d] = dx[t+k+3][d] - sum_j ph[d][j]*dx[t+k+2-j][d]
        float q2 = 0.0f;
        #pragma unroll
        for (int k = 0; k < 4; ++k) {
            #pragma unroll
            for (int d = 0; d < D; ++d) {
                float dy = dxv[(k + 3) * 3 + d]
                         - (ph[d][0] * dxv[(k + 2) * 3 + d]
                          + ph[d][1] * dxv[(k + 1) * 3 + d]
                          + ph[d][2] * dxv[k * 3 + d]);
                float z = dy - cc[d];
                q2 = fmaf(z * z, inv_s2[d], q2);
            }
        }
        acc = -0.5f * (float)NK * q2;          // -5.5 * sum(z^2/s^2)
    }

    // Wave shuffle reduction, then cross-wave via LDS; one store/block.
    #pragma unroll
    for (int off = 32; off > 0; off >>= 1) acc += __shfl_down(acc, off, 64);
    const int wave = tid >> 6, lane = tid & 63;
    if (lane == 0) wave_sums[wave] = acc;
    __syncthreads();
    if (tid == 0) {
        float block_sum = wave_sums[0] + wave_sums[1] + wave_sums[2] + wave_sums[3];
        int cnt = TP - half * OUT_PER_BLOCK;   // valid outputs in this block
        if (cnt > OUT_PER_BLOCK) cnt = OUT_PER_BLOCK;
        block_sum += (float)cnt * Cd_sum;      // analytic winding constant
        if (use_ws) {
            partial[blk] = block_sum;          // disjoint plain store
        } else {
            const int mc = series / n_samples;
            atomicAdd(&out[mc], block_sum);    // fallback (round-0 semantics)
        }
    }
}

// Block mc sums its per_mc contiguous partials and writes out[mc] directly.
// Cross-kernel visibility of `partial` is guaranteed by the dispatch-boundary
// release/acquire (no fences needed).
__global__ __launch_bounds__(64) void reduce_kernel(
    const float* __restrict__ partial,
    float* __restrict__ out,
    int per_mc)
{
    const int mc = blockIdx.x;
    float v = 0.0f;
    for (int i = threadIdx.x; i < per_mc; i += 64)
        v += partial[(size_t)mc * per_mc + i];
    #pragma unroll
    for (int off = 32; off > 0; off >>= 1) v += __shfl_down(v, off, 64);
    if (threadIdx.x == 0) out[mc] = v;
}

extern "C" void kernel_launch(void* const* d_in, const int* in_sizes, int n_in,
                              void* d_out, int out_size, void* d_ws, size_t ws_size,
                              hipStream_t stream) {
    const float* g      = (const float*)d_in[0];
    const float* ar_phi = (const float*)d_in[1];
    const float* ar_eta = (const float*)d_in[2];
    const float* ar_c   = (const float*)d_in[3];
    float* out = (float*)d_out;

    const int n_series  = in_sizes[0] / (T * D);       // n_mc * n_samples = 512
    const int n_mc      = out_size;                    // 32
    const int n_samples = n_series / n_mc;             // 16
    const int n_blocks  = n_series * BLOCKS_PER_SERIES;// 1024
    const int per_mc    = n_samples * BLOCKS_PER_SERIES;// 32 partials per mc

    const int use_ws = (d_ws != nullptr &&
                        ws_size >= (size_t)n_blocks * sizeof(float)) ? 1 : 0;
    float* partial = (float*)d_ws;

    if (!use_ws) {
        // d_out is poisoned (0xAA) before every timed launch — zero it.
        hipMemsetAsync(out, 0, (size_t)out_size * sizeof(float), stream);
    }
    arp_kernel<<<n_blocks, 256, 0, stream>>>(g, ar_phi, ar_eta, ar_c,
                                             partial, out, n_samples, use_ws);
    if (use_ws)
        reduce_kernel<<<n_mc, 64, 0, stream>>>(partial, out, per_mc);
}